// Round 1
// baseline (3458.723 us; speedup 1.0000x reference)
//
#include <hip/hip_runtime.h>
#include <math.h>

#define NB 8
#define PP 2048
#define DD 64
#define EPSF 1e-3f
#define RCPE 1000.0f
#define TMAX 10
#define THRESHF 0.1f

__device__ __forceinline__ float waveReduceSum(float v) {
#pragma unroll
    for (int off = 32; off > 0; off >>= 1) v += __shfl_down(v, off, 64);
    return v;
}
__device__ __forceinline__ float waveReduceMax(float v) {
#pragma unroll
    for (int off = 32; off > 0; off >>= 1) v = fmaxf(v, __shfl_down(v, off, 64));
    return v;
}
// 256-thread block reduce, result broadcast to all threads
__device__ __forceinline__ float blockReduceSum256(float v, float* sh) {
    v = waveReduceSum(v);
    int lane = threadIdx.x & 63, w = threadIdx.x >> 6;
    if (lane == 0) sh[w] = v;
    __syncthreads();
    float r = sh[0] + sh[1] + sh[2] + sh[3];
    __syncthreads();
    return r;
}
__device__ __forceinline__ float blockReduceMax256(float v, float* sh) {
    v = waveReduceMax(v);
    int lane = threadIdx.x & 63, w = threadIdx.x >> 6;
    if (lane == 0) sh[w] = v;
    __syncthreads();
    float r = fmaxf(fmaxf(sh[0], sh[1]), fmaxf(sh[2], sh[3]));
    __syncthreads();
    return r;
}

// ---- init: zero u, v, scalars, out -----------------------------------------
__global__ void init_kernel(float* u, float* v, float* err, int* conv, float* out) {
    int t = blockIdx.x * 256 + threadIdx.x;   // 32768 threads total
    if (t < NB * PP) u[t] = 0.0f;
    else             v[t - NB * PP] = 0.0f;
    if (t == 0) { *err = 0.0f; *conv = 0; }
    if (t < NB) out[t] = 0.0f;
}

// ---- L2 normalize: one wave per row (rows of a then b) ---------------------
__global__ void norm_kernel(const float* __restrict__ a, const float* __restrict__ b,
                            float* __restrict__ an, float* __restrict__ bn) {
    int wave = (blockIdx.x * blockDim.x + threadIdx.x) >> 6;
    int lane = threadIdx.x & 63;
    const float* src; float* dst; int row;
    if (wave < NB * PP) { src = a; dst = an; row = wave; }
    else                { src = b; dst = bn; row = wave - NB * PP; }
    float x = src[(size_t)row * DD + lane];
    float ss = x * x;
    ss = waveReduceSum(ss);
    ss = __shfl(ss, 0, 64);
    float r = 1.0f / fmaxf(sqrtf(ss), 1e-12f);
    dst[(size_t)row * DD + lane] = x * r;
}

// ---- cost GEMM: C = 1 - an @ bn^T, 64x64 tile per 256-thread block ---------
#define LDA 68   // padded LDS stride (floats): keeps float4 alignment, breaks bank conflicts
__global__ __launch_bounds__(256) void cost_kernel(const float* __restrict__ an,
                                                   const float* __restrict__ bn,
                                                   float* __restrict__ C) {
    int b  = blockIdx.z;
    int i0 = blockIdx.y * 64;
    int j0 = blockIdx.x * 64;
    __shared__ float As[64][LDA];  // [k][i]
    __shared__ float Bs[64][LDA];  // [k][j]
    int tid = threadIdx.x;
    {
        int r  = tid >> 2;            // row within tile 0..63
        int c4 = (tid & 3) * 16;      // k base (each thread: 16 k as 4 float4)
        const float4* pa = (const float4*)&an[((size_t)b * PP + i0 + r) * DD + c4];
        const float4* pb = (const float4*)&bn[((size_t)b * PP + j0 + r) * DD + c4];
#pragma unroll
        for (int q = 0; q < 4; ++q) {
            float4 va = pa[q]; float4 vb = pb[q];
            int k = c4 + q * 4;
            As[k+0][r] = va.x; As[k+1][r] = va.y; As[k+2][r] = va.z; As[k+3][r] = va.w;
            Bs[k+0][r] = vb.x; Bs[k+1][r] = vb.y; Bs[k+2][r] = vb.z; Bs[k+3][r] = vb.w;
        }
    }
    __syncthreads();
    int tx = tid & 15, ty = tid >> 4;
    float acc[4][4] = {};
#pragma unroll 8
    for (int k = 0; k < 64; ++k) {
        float4 av = *(const float4*)&As[k][ty * 4];
        float4 bv = *(const float4*)&Bs[k][tx * 4];
        float aa[4] = {av.x, av.y, av.z, av.w};
        float bb[4] = {bv.x, bv.y, bv.z, bv.w};
#pragma unroll
        for (int r = 0; r < 4; ++r)
#pragma unroll
            for (int c = 0; c < 4; ++c)
                acc[r][c] += aa[r] * bb[c];
    }
#pragma unroll
    for (int r = 0; r < 4; ++r) {
        int i = i0 + ty * 4 + r;
        float4 o;
        o.x = 1.0f - acc[r][0]; o.y = 1.0f - acc[r][1];
        o.z = 1.0f - acc[r][2]; o.w = 1.0f - acc[r][3];
        *(float4*)&C[((size_t)b * PP + i) * PP + j0 + tx * 4] = o;
    }
}

// ---- row sums of S = 1 - C: one block per (b,i) ----------------------------
__global__ void rowsum_kernel(const float* __restrict__ C, float* __restrict__ rowsum) {
    __shared__ float sh[4];
    int bi = blockIdx.x;
    const float* row = &C[(size_t)bi * PP];
    int tid = threadIdx.x;
    float s = 0.0f;
#pragma unroll
    for (int q = 0; q < 8; ++q) s += row[tid + q * 256];
    s = blockReduceSum256(s, sh);
    if (tid == 0) rowsum[bi] = (float)PP - s;
}

// ---- col sums of S: 64-column tile per block, 4-way row split --------------
__global__ void colsum_kernel(const float* __restrict__ C, float* __restrict__ colsum) {
    int b  = blockIdx.y;
    int j0 = blockIdx.x * 64;
    int tid = threadIdx.x;
    int c = tid & 63, rs = tid >> 6;
    const float* base = &C[(size_t)b * PP * PP];
    float s = 0.0f;
    for (int i = rs; i < PP; i += 4) s += base[(size_t)i * PP + j0 + c];
    __shared__ float red[4][64];
    red[rs][c] = s;
    __syncthreads();
    if (rs == 0) {
        float t = red[0][c] + red[1][c] + red[2][c] + red[3][c];
        colsum[b * PP + j0 + c] = (float)PP - t;
    }
}

// ---- weights: l1norm(clip(l1norm(mean(S)))) then store eps*log(w + 1e-8) ---
__global__ void weights_kernel(const float* __restrict__ rowsum, const float* __restrict__ colsum,
                               float* __restrict__ elm, float* __restrict__ eln) {
    __shared__ float sh[4];
    int b = blockIdx.x & 7;
    bool isB = blockIdx.x >= 8;
    const float* src = (isB ? colsum : rowsum) + b * PP;
    float* dst = (isB ? eln : elm) + b * PP;
    int tid = threadIdx.x;
    float x[8];
    float sabs = 0.0f;
#pragma unroll
    for (int q = 0; q < 8; ++q) {
        x[q] = src[tid + q * 256] * (1.0f / (float)PP);   // mean
        sabs += fabsf(x[q]);
    }
    sabs = blockReduceSum256(sabs, sh);
    float inv1 = 1.0f / fmaxf(sabs, 1e-12f);
    float spos = 0.0f;
#pragma unroll
    for (int q = 0; q < 8; ++q) {
        x[q] = fmaxf(x[q] * inv1, 0.0f);                  // clip(l1norm)
        spos += x[q];
    }
    spos = blockReduceSum256(spos, sh);
    float inv2 = 1.0f / fmaxf(spos, 1e-12f);
#pragma unroll
    for (int q = 0; q < 8; ++q)
        dst[tid + q * 256] = EPSF * logf(x[q] * inv2 + 1e-8f);
}

// ---- u update: u = elm - eps*LSE_j((v_j - C_ij)/eps); accumulate |du| ------
__global__ void u_update_kernel(const float* __restrict__ C, const float* __restrict__ v,
                                const float* __restrict__ elm, float* __restrict__ u,
                                float* __restrict__ err_accum, const int* __restrict__ conv) {
    if (*conv) return;
    __shared__ float sh[4];
    int bi = blockIdx.x;
    int b = bi >> 11;
    const float* row = &C[(size_t)bi * PP];
    const float* vb  = &v[b * PP];
    int tid = threadIdx.x;
    float x[8];
    float m = -1e30f;
#pragma unroll
    for (int q = 0; q < 8; ++q) {
        int j = tid + q * 256;
        x[q] = vb[j] - row[j];
        m = fmaxf(m, x[q]);
    }
    m = blockReduceMax256(m, sh);
    float s = 0.0f;
#pragma unroll
    for (int q = 0; q < 8; ++q) s += expf((x[q] - m) * RCPE);
    s = blockReduceSum256(s, sh);
    if (tid == 0) {
        float unew = elm[bi] - (m + EPSF * logf(s));
        float du = fabsf(unew - u[bi]);
        u[bi] = unew;
        atomicAdd(err_accum, du);
    }
}

// ---- v update: v = eln - eps*LSE_i((u_i - C_ij)/eps) -----------------------
__global__ void v_update_kernel(const float* __restrict__ C, const float* __restrict__ u,
                                const float* __restrict__ eln, float* __restrict__ v,
                                const int* __restrict__ conv) {
    if (*conv) return;
    int b  = blockIdx.y;
    int j0 = blockIdx.x * 64;
    int tid = threadIdx.x;
    int c = tid & 63, rs = tid >> 6;
    int jc = j0 + c;
    const float* base = &C[(size_t)b * PP * PP];
    const float* ub   = &u[b * PP];
    float m = -1e30f, s = 0.0f;
    for (int i = rs; i < PP; i += 16) {
        float x0 = ub[i]      - base[(size_t)(i)      * PP + jc];
        float x1 = ub[i + 4]  - base[(size_t)(i + 4)  * PP + jc];
        float x2 = ub[i + 8]  - base[(size_t)(i + 8)  * PP + jc];
        float x3 = ub[i + 12] - base[(size_t)(i + 12) * PP + jc];
        float mn;
        mn = fmaxf(m, x0); s = s * expf((m - mn) * RCPE) + expf((x0 - mn) * RCPE); m = mn;
        mn = fmaxf(m, x1); s = s * expf((m - mn) * RCPE) + expf((x1 - mn) * RCPE); m = mn;
        mn = fmaxf(m, x2); s = s * expf((m - mn) * RCPE) + expf((x2 - mn) * RCPE); m = mn;
        mn = fmaxf(m, x3); s = s * expf((m - mn) * RCPE) + expf((x3 - mn) * RCPE); m = mn;
    }
    __shared__ float Ms[4][64], Ss[4][64];
    Ms[rs][c] = m; Ss[rs][c] = s;
    __syncthreads();
    if (rs == 0) {
        float mm = m, ss = s;
#pragma unroll
        for (int q = 1; q < 4; ++q) {
            float m2 = Ms[q][c], s2 = Ss[q][c];
            float mn = fmaxf(mm, m2);
            ss = ss * expf((mm - mn) * RCPE) + s2 * expf((m2 - mn) * RCPE);
            mm = mn;
        }
        v[b * PP + jc] = eln[b * PP + jc] - (mm + EPSF * logf(ss));
    }
}

// ---- err finalize: err = accum/N; set converged; reset accum ---------------
__global__ void finalize_err_kernel(float* err_accum, int* conv) {
    if (*conv) return;
    float err = *err_accum * (1.0f / (float)NB);
    if (err < THRESHF) *conv = 1;
    *err_accum = 0.0f;
}

// ---- final: D[b] = sum_ij exp((u_i + v_j - C_ij)/eps) * C_ij ---------------
__global__ void emd_kernel(const float* __restrict__ C, const float* __restrict__ u,
                           const float* __restrict__ v, float* __restrict__ out) {
    __shared__ float sh[4];
    int bi = blockIdx.x;
    int b = bi >> 11;
    const float* row = &C[(size_t)bi * PP];
    const float* vb  = &v[b * PP];
    float ui = u[bi];
    int tid = threadIdx.x;
    float s = 0.0f;
#pragma unroll
    for (int q = 0; q < 8; ++q) {
        int j = tid + q * 256;
        float cc = row[j];
        s += expf((ui + vb[j] - cc) * RCPE) * cc;
    }
    s = blockReduceSum256(s, sh);
    if (tid == 0) atomicAdd(&out[b], s);
}

extern "C" void kernel_launch(void* const* d_in, const int* in_sizes, int n_in,
                              void* d_out, int out_size, void* d_ws, size_t ws_size,
                              hipStream_t stream) {
    const float* a = (const float*)d_in[0];
    const float* b = (const float*)d_in[1];
    float* out = (float*)d_out;

    char* ws = (char*)d_ws;
    size_t off = 0;
    const size_t szC  = (size_t)NB * PP * PP * 4;
    const size_t szAN = (size_t)NB * PP * DD * 4;
    const size_t szV  = (size_t)NB * PP * 4;
    float* C       = (float*)(ws + off); off += szC;
    float* an      = (float*)(ws + off); off += szAN;
    float* bn      = (float*)(ws + off); off += szAN;
    float* rowsum  = (float*)(ws + off); off += szV;
    float* colsum  = (float*)(ws + off); off += szV;
    float* elm     = (float*)(ws + off); off += szV;
    float* eln     = (float*)(ws + off); off += szV;
    float* u       = (float*)(ws + off); off += szV;
    float* v       = (float*)(ws + off); off += szV;
    float* err     = (float*)(ws + off); off += 64;
    int*   conv    = (int*)  (ws + off); off += 64;
    if (ws_size < off) return;  // workspace too small — fail loudly via wrong output

    init_kernel<<<128, 256, 0, stream>>>(u, v, err, conv, out);
    norm_kernel<<<(2 * NB * PP) / 4, 256, 0, stream>>>(a, b, an, bn);
    cost_kernel<<<dim3(PP / 64, PP / 64, NB), 256, 0, stream>>>(an, bn, C);
    rowsum_kernel<<<NB * PP, 256, 0, stream>>>(C, rowsum);
    colsum_kernel<<<dim3(PP / 64, NB), 256, 0, stream>>>(C, colsum);
    weights_kernel<<<16, 256, 0, stream>>>(rowsum, colsum, elm, eln);
    for (int it = 0; it < TMAX; ++it) {
        u_update_kernel<<<NB * PP, 256, 0, stream>>>(C, v, elm, u, err, conv);
        v_update_kernel<<<dim3(PP / 64, NB), 256, 0, stream>>>(C, u, eln, v, conv);
        finalize_err_kernel<<<1, 1, 0, stream>>>(err, conv);
    }
    emd_kernel<<<NB * PP, 256, 0, stream>>>(C, u, v, out);
}

// Round 2
// 765.269 us; speedup vs baseline: 4.5196x; 4.5196x over previous
//
#include <hip/hip_runtime.h>
#include <math.h>

#define NB 8
#define PP 2048
#define DD 64
#define EPSF 1e-3f
#define RCPE 1000.0f
#define TMAX 10
#define THRESHF 0.1f
#define NEG_INF (-1e30f)

__device__ __forceinline__ float waveAllMax(float v) {
#pragma unroll
    for (int m = 1; m < 64; m <<= 1) v = fmaxf(v, __shfl_xor(v, m, 64));
    return v;
}
__device__ __forceinline__ float waveAllSum(float v) {
#pragma unroll
    for (int m = 1; m < 64; m <<= 1) v += __shfl_xor(v, m, 64);
    return v;
}

// ---- init: zero u, v, conv, out --------------------------------------------
__global__ void init_kernel(float* u, float* v, int* conv, float* out) {
    int t = blockIdx.x * 256 + threadIdx.x;   // 32768 threads
    if (t < NB * PP) u[t] = 0.0f;
    else             v[t - NB * PP] = 0.0f;
    if (t == 0) *conv = 0;
    if (t < NB) out[t] = 0.0f;
}

// ---- L2 normalize: one wave per row ----------------------------------------
__global__ void norm_kernel(const float* __restrict__ a, const float* __restrict__ b,
                            float* __restrict__ an, float* __restrict__ bn) {
    int wave = (blockIdx.x * blockDim.x + threadIdx.x) >> 6;
    int lane = threadIdx.x & 63;
    const float* src; float* dst; int row;
    if (wave < NB * PP) { src = a; dst = an; row = wave; }
    else                { src = b; dst = bn; row = wave - NB * PP; }
    float x = src[(size_t)row * DD + lane];
    float ss = waveAllSum(x * x);
    float r = 1.0f / fmaxf(sqrtf(ss), 1e-12f);
    dst[(size_t)row * DD + lane] = x * r;
}

// ---- cost GEMM: C = 1 - an @ bn^T, 64x64 tile per 256-thread block ---------
#define LDA 68
__global__ __launch_bounds__(256) void cost_kernel(const float* __restrict__ an,
                                                   const float* __restrict__ bn,
                                                   float* __restrict__ C) {
    int b  = blockIdx.z;
    int i0 = blockIdx.y * 64;
    int j0 = blockIdx.x * 64;
    __shared__ float As[64][LDA];  // [k][i]
    __shared__ float Bs[64][LDA];  // [k][j]
    int tid = threadIdx.x;
    {
        int r  = tid >> 2;
        int c4 = (tid & 3) * 16;
        const float4* pa = (const float4*)&an[((size_t)b * PP + i0 + r) * DD + c4];
        const float4* pb = (const float4*)&bn[((size_t)b * PP + j0 + r) * DD + c4];
#pragma unroll
        for (int q = 0; q < 4; ++q) {
            float4 va = pa[q]; float4 vb = pb[q];
            int k = c4 + q * 4;
            As[k+0][r] = va.x; As[k+1][r] = va.y; As[k+2][r] = va.z; As[k+3][r] = va.w;
            Bs[k+0][r] = vb.x; Bs[k+1][r] = vb.y; Bs[k+2][r] = vb.z; Bs[k+3][r] = vb.w;
        }
    }
    __syncthreads();
    int tx = tid & 15, ty = tid >> 4;
    float acc[4][4] = {};
#pragma unroll 8
    for (int k = 0; k < 64; ++k) {
        float4 av = *(const float4*)&As[k][ty * 4];
        float4 bv = *(const float4*)&Bs[k][tx * 4];
        float aa[4] = {av.x, av.y, av.z, av.w};
        float bb[4] = {bv.x, bv.y, bv.z, bv.w};
#pragma unroll
        for (int r = 0; r < 4; ++r)
#pragma unroll
            for (int c = 0; c < 4; ++c)
                acc[r][c] += aa[r] * bb[c];
    }
#pragma unroll
    for (int r = 0; r < 4; ++r) {
        int i = i0 + ty * 4 + r;
        float4 o;
        o.x = 1.0f - acc[r][0]; o.y = 1.0f - acc[r][1];
        o.z = 1.0f - acc[r][2]; o.w = 1.0f - acc[r][3];
        *(float4*)&C[((size_t)b * PP + i) * PP + j0 + tx * 4] = o;
    }
}

// ---- row sums: wave per row, float4, shuffle-only --------------------------
__global__ __launch_bounds__(256) void rowsum_kernel(const float* __restrict__ C,
                                                     float* __restrict__ rowsum) {
    int wv = threadIdx.x >> 6, lane = threadIdx.x & 63;
    int bi = blockIdx.x * 4 + wv;
    const float4* row = (const float4*)&C[(size_t)bi * PP];
    float s = 0.0f;
#pragma unroll
    for (int q = 0; q < 8; ++q) { float4 c = row[q * 64 + lane]; s += c.x + c.y + c.z + c.w; }
    s = waveAllSum(s);
    if (lane == 0) rowsum[bi] = (float)PP - s;
}

// ---- col sums, tiled partials: thread owns 4 cols over 64 rows -------------
__global__ __launch_bounds__(256) void colsum_part_kernel(const float* __restrict__ C,
                                                          float* __restrict__ cpart) {
    int jt = blockIdx.x, rc = blockIdx.y, b = blockIdx.z;
    int j = jt * 1024 + threadIdx.x * 4;
    int r0 = rc * 64;
    const float* base = &C[((size_t)b * PP + r0) * PP + j];
    float4 acc = make_float4(0.f, 0.f, 0.f, 0.f);
#pragma unroll 8
    for (int i = 0; i < 64; ++i) {
        float4 c = *(const float4*)(base + (size_t)i * PP);
        acc.x += c.x; acc.y += c.y; acc.z += c.z; acc.w += c.w;
    }
    *(float4*)&cpart[(size_t)(rc * 8 + b) * PP + j] = acc;
}

__global__ void colsum_combine_kernel(const float* __restrict__ cpart,
                                      float* __restrict__ colsum) {
    int idx = blockIdx.x * 256 + threadIdx.x;   // 64 blocks -> 16384
    float s = 0.0f;
#pragma unroll
    for (int rc = 0; rc < 32; ++rc) s += cpart[(size_t)rc * (8 * PP) + idx];
    colsum[idx] = (float)PP - s;
}

// ---- weights: l1norm(clip(l1norm(mean(S)))) then store eps*log(w + 1e-8) ---
__device__ __forceinline__ float blockReduceSum256(float v, float* sh) {
    v = waveAllSum(v);
    int lane = threadIdx.x & 63, w = threadIdx.x >> 6;
    if (lane == 0) sh[w] = v;
    __syncthreads();
    float r = sh[0] + sh[1] + sh[2] + sh[3];
    __syncthreads();
    return r;
}

__global__ void weights_kernel(const float* __restrict__ rowsum, const float* __restrict__ colsum,
                               float* __restrict__ elm, float* __restrict__ eln) {
    __shared__ float sh[4];
    int b = blockIdx.x & 7;
    bool isB = blockIdx.x >= 8;
    const float* src = (isB ? colsum : rowsum) + b * PP;
    float* dst = (isB ? eln : elm) + b * PP;
    int tid = threadIdx.x;
    float x[8];
    float sabs = 0.0f;
#pragma unroll
    for (int q = 0; q < 8; ++q) {
        x[q] = src[tid + q * 256] * (1.0f / (float)PP);
        sabs += fabsf(x[q]);
    }
    sabs = blockReduceSum256(sabs, sh);
    float inv1 = 1.0f / fmaxf(sabs, 1e-12f);
    float spos = 0.0f;
#pragma unroll
    for (int q = 0; q < 8; ++q) {
        x[q] = fmaxf(x[q] * inv1, 0.0f);
        spos += x[q];
    }
    spos = blockReduceSum256(spos, sh);
    float inv2 = 1.0f / fmaxf(spos, 1e-12f);
#pragma unroll
    for (int q = 0; q < 8; ++q)
        dst[tid + q * 256] = EPSF * logf(x[q] * inv2 + 1e-8f);
}

// ---- u update: wave per row, float4, shuffle-only; du -> array -------------
__global__ __launch_bounds__(256) void u_update_kernel(const float* __restrict__ C,
        const float* __restrict__ v, const float* __restrict__ elm,
        float* __restrict__ u, float* __restrict__ du, const int* __restrict__ conv) {
    if (*conv) return;
    int wv = threadIdx.x >> 6, lane = threadIdx.x & 63;
    int bi = blockIdx.x * 4 + wv;
    int b = bi >> 11;
    const float4* row = (const float4*)&C[(size_t)bi * PP];
    const float4* vb  = (const float4*)&v[b * PP];
    float x[32];
    float m = NEG_INF;
#pragma unroll
    for (int q = 0; q < 8; ++q) {
        float4 c = row[q * 64 + lane];
        float4 vv = vb[q * 64 + lane];
        x[q*4+0] = vv.x - c.x; x[q*4+1] = vv.y - c.y;
        x[q*4+2] = vv.z - c.z; x[q*4+3] = vv.w - c.w;
        m = fmaxf(m, fmaxf(fmaxf(x[q*4+0], x[q*4+1]), fmaxf(x[q*4+2], x[q*4+3])));
    }
    m = waveAllMax(m);
    float s = 0.0f;
#pragma unroll
    for (int k = 0; k < 32; ++k) s += __expf((x[k] - m) * RCPE);
    s = waveAllSum(s);
    if (lane == 0) {
        float unew = elm[bi] - m - EPSF * logf(s);
        du[bi] = fabsf(unew - u[bi]);
        u[bi] = unew;
    }
}

// ---- err reduce: one 1024-thread block; sets conv --------------------------
__global__ __launch_bounds__(1024) void err_reduce_kernel(const float* __restrict__ du,
                                                          int* __restrict__ conv) {
    if (*conv) return;
    __shared__ float sh[16];
    int t = threadIdx.x;
    float s = 0.0f;
#pragma unroll
    for (int q = 0; q < 16; ++q) s += du[t + q * 1024];
    s = waveAllSum(s);
    if ((t & 63) == 0) sh[t >> 6] = s;
    __syncthreads();
    if (t == 0) {
        float tot = 0.0f;
#pragma unroll
        for (int w = 0; w < 16; ++w) tot += sh[w];
        if (tot * (1.0f / (float)NB) < THRESHF) *conv = 1;
    }
}

// ---- v update partials: thread owns 4 cols, online LSE over 64 rows --------
__global__ __launch_bounds__(256) void v_part_kernel(const float* __restrict__ C,
        const float* __restrict__ u, float* __restrict__ vmp, float* __restrict__ vsp,
        const int* __restrict__ conv) {
    if (*conv) return;
    int jt = blockIdx.x, rc = blockIdx.y, b = blockIdx.z;
    int j = jt * 1024 + threadIdx.x * 4;
    int r0 = rc * 64;
    __shared__ float ush[64];
    if (threadIdx.x < 64) ush[threadIdx.x] = u[b * PP + r0 + threadIdx.x];
    __syncthreads();
    const float* base = &C[((size_t)b * PP + r0) * PP + j];
    float m[4] = {NEG_INF, NEG_INF, NEG_INF, NEG_INF};
    float s[4] = {0.f, 0.f, 0.f, 0.f};
    for (int g = 0; g < 8; ++g) {
        float4 c[8];
#pragma unroll
        for (int k = 0; k < 8; ++k) c[k] = *(const float4*)(base + (size_t)(g * 8 + k) * PP);
        float uu[8];
#pragma unroll
        for (int k = 0; k < 8; ++k) uu[k] = ush[g * 8 + k];
#pragma unroll
        for (int col = 0; col < 4; ++col) {
            float x[8];
#pragma unroll
            for (int k = 0; k < 8; ++k) {
                float cc = (col == 0) ? c[k].x : (col == 1) ? c[k].y : (col == 2) ? c[k].z : c[k].w;
                x[k] = uu[k] - cc;
            }
            float gm = x[0];
#pragma unroll
            for (int k = 1; k < 8; ++k) gm = fmaxf(gm, x[k]);
            float nm = fmaxf(m[col], gm);
            float acc = 0.0f;
#pragma unroll
            for (int k = 0; k < 8; ++k) acc += __expf((x[k] - nm) * RCPE);
            s[col] = s[col] * __expf((m[col] - nm) * RCPE) + acc;
            m[col] = nm;
        }
    }
    size_t o = (size_t)(rc * 8 + b) * PP + j;
    *(float4*)&vmp[o] = make_float4(m[0], m[1], m[2], m[3]);
    *(float4*)&vsp[o] = make_float4(s[0], s[1], s[2], s[3]);
}

__global__ void v_combine_kernel(const float* __restrict__ vmp, const float* __restrict__ vsp,
                                 const float* __restrict__ eln, float* __restrict__ v,
                                 const int* __restrict__ conv) {
    if (*conv) return;
    int idx = blockIdx.x * 256 + threadIdx.x;   // 64 blocks -> 16384
    float M = NEG_INF, S = 0.0f;
#pragma unroll
    for (int rc = 0; rc < 32; ++rc) {
        float m2 = vmp[(size_t)rc * (8 * PP) + idx];
        float s2 = vsp[(size_t)rc * (8 * PP) + idx];
        float nm = fmaxf(M, m2);
        S = S * __expf((M - nm) * RCPE) + s2 * __expf((m2 - nm) * RCPE);
        M = nm;
    }
    v[idx] = eln[idx] - M - EPSF * logf(S);
}

// ---- final: D[b] = sum_ij exp((u_i + v_j - C_ij)/eps) * C_ij ---------------
__global__ __launch_bounds__(256) void emd_kernel(const float* __restrict__ C,
        const float* __restrict__ u, const float* __restrict__ v, float* __restrict__ out) {
    __shared__ float sh[4];
    int wv = threadIdx.x >> 6, lane = threadIdx.x & 63;
    int bi = blockIdx.x * 4 + wv;
    int b = bi >> 11;
    const float4* row = (const float4*)&C[(size_t)bi * PP];
    const float4* vb  = (const float4*)&v[b * PP];
    float ui = u[bi];
    float s = 0.0f;
#pragma unroll
    for (int q = 0; q < 8; ++q) {
        float4 c = row[q * 64 + lane];
        float4 vv = vb[q * 64 + lane];
        s += __expf((ui + vv.x - c.x) * RCPE) * c.x;
        s += __expf((ui + vv.y - c.y) * RCPE) * c.y;
        s += __expf((ui + vv.z - c.z) * RCPE) * c.z;
        s += __expf((ui + vv.w - c.w) * RCPE) * c.w;
    }
    s = waveAllSum(s);
    if (lane == 0) sh[wv] = s;
    __syncthreads();
    if (threadIdx.x == 0) atomicAdd(&out[b], sh[0] + sh[1] + sh[2] + sh[3]);
}

extern "C" void kernel_launch(void* const* d_in, const int* in_sizes, int n_in,
                              void* d_out, int out_size, void* d_ws, size_t ws_size,
                              hipStream_t stream) {
    const float* a = (const float*)d_in[0];
    const float* b = (const float*)d_in[1];
    float* out = (float*)d_out;

    char* ws = (char*)d_ws;
    size_t off = 0;
    const size_t szC  = (size_t)NB * PP * PP * 4;   // 128 MB
    const size_t szAN = (size_t)NB * PP * DD * 4;   // 4 MB
    const size_t szV  = (size_t)NB * PP * 4;        // 64 KB
    float* C       = (float*)(ws + off); off += szC;
    float* an      = (float*)(ws + off); off += szAN;
    float* bn      = (float*)(ws + off); off += szAN;
    float* rowsum  = (float*)(ws + off); off += szV;
    float* colsum  = (float*)(ws + off); off += szV;
    float* elm     = (float*)(ws + off); off += szV;
    float* eln     = (float*)(ws + off); off += szV;
    float* u       = (float*)(ws + off); off += szV;
    float* v       = (float*)(ws + off); off += szV;
    float* du      = (float*)(ws + off); off += szV;
    int*   conv    = (int*)  (ws + off); off += 64;
    if (ws_size < off) return;
    // aliases: an/bn are dead after cost_kernel; partials live there afterwards
    float* cpart = an;   // 2 MB, used pre-loop (after cost_kernel)
    float* vmp   = an;   // 2 MB, used in loop
    float* vsp   = bn;   // 2 MB, used in loop

    init_kernel<<<128, 256, 0, stream>>>(u, v, conv, out);
    norm_kernel<<<(2 * NB * PP) / 4, 256, 0, stream>>>(a, b, an, bn);
    cost_kernel<<<dim3(PP / 64, PP / 64, NB), 256, 0, stream>>>(an, bn, C);
    rowsum_kernel<<<NB * PP / 4, 256, 0, stream>>>(C, rowsum);
    colsum_part_kernel<<<dim3(2, 32, NB), 256, 0, stream>>>(C, cpart);
    colsum_combine_kernel<<<64, 256, 0, stream>>>(cpart, colsum);
    weights_kernel<<<16, 256, 0, stream>>>(rowsum, colsum, elm, eln);
    for (int it = 0; it < TMAX; ++it) {
        u_update_kernel<<<NB * PP / 4, 256, 0, stream>>>(C, v, elm, u, du, conv);
        v_part_kernel<<<dim3(2, 32, NB), 256, 0, stream>>>(C, u, vmp, vsp, conv);
        v_combine_kernel<<<64, 256, 0, stream>>>(vmp, vsp, eln, v, conv);
        err_reduce_kernel<<<1, 1024, 0, stream>>>(du, conv);
    }
    emd_kernel<<<NB * PP / 4, 256, 0, stream>>>(C, u, v, out);
}

// Round 3
// 615.642 us; speedup vs baseline: 5.6181x; 1.2430x over previous
//
#include <hip/hip_runtime.h>
#include <math.h>

#define NB 8
#define PP 2048
#define DD 64
#define EPSF 1e-3f
#define RCPE 1000.0f
#define TMAX 10
#define THRESHF 0.1f
#define NEG_INF (-1e30f)
#define QSCALE 32767.5f                 // cost in [0,2] -> u16
#define S_DEQ  (1.0f / 32767.5f)

__device__ __forceinline__ float waveAllMax(float v) {
#pragma unroll
    for (int m = 1; m < 64; m <<= 1) v = fmaxf(v, __shfl_xor(v, m, 64));
    return v;
}
__device__ __forceinline__ float waveAllSum(float v) {
#pragma unroll
    for (int m = 1; m < 64; m <<= 1) v += __shfl_xor(v, m, 64);
    return v;
}

// ---- init: zero u, v, rowS, colS, conv, out --------------------------------
__global__ void init_kernel(float* u, float* v, float* rowS, float* colS,
                            int* conv, float* out) {
    int t = blockIdx.x * 256 + threadIdx.x;   // 16384 threads
    u[t] = 0.0f; v[t] = 0.0f; rowS[t] = 0.0f; colS[t] = 0.0f;
    if (t == 0) *conv = 0;
    if (t < NB) out[t] = 0.0f;
}

// ---- L2 normalize: one wave per row ----------------------------------------
__global__ void norm_kernel(const float* __restrict__ a, const float* __restrict__ b,
                            float* __restrict__ an, float* __restrict__ bn) {
    int wave = (blockIdx.x * blockDim.x + threadIdx.x) >> 6;
    int lane = threadIdx.x & 63;
    const float* src; float* dst; int row;
    if (wave < NB * PP) { src = a; dst = an; row = wave; }
    else                { src = b; dst = bn; row = wave - NB * PP; }
    float x = src[(size_t)row * DD + lane];
    float ss = waveAllSum(x * x);
    float r = 1.0f / fmaxf(sqrtf(ss), 1e-12f);
    dst[(size_t)row * DD + lane] = x * r;
}

// ---- cost GEMM: C16 = quantize(1 - an@bn^T); fused row/col sums of S=dot ---
// LDS layout [k][col] with col = r ^ (k&16): write banks 2-way (free), reads
// stay float4-aligned.
#define LDA 68
__global__ __launch_bounds__(256) void cost_kernel(const float* __restrict__ an,
                                                   const float* __restrict__ bn,
                                                   unsigned short* __restrict__ C16,
                                                   float* __restrict__ rowS,
                                                   float* __restrict__ colS) {
    int b  = blockIdx.z;
    int i0 = blockIdx.y * 64;
    int j0 = blockIdx.x * 64;
    __shared__ float As[64][LDA];  // [k][i^ (k&16)]
    __shared__ float Bs[64][LDA];  // [k][j^ (k&16)]
    __shared__ float csum_s[64];
    int tid = threadIdx.x;
    if (tid < 64) csum_s[tid] = 0.0f;
    {
        int r  = tid >> 2;
        int c4 = (tid & 3) * 16;
        const float4* pa = (const float4*)&an[((size_t)b * PP + i0 + r) * DD + c4];
        const float4* pb = (const float4*)&bn[((size_t)b * PP + j0 + r) * DD + c4];
#pragma unroll
        for (int q = 0; q < 4; ++q) {
            float4 va = pa[q]; float4 vb = pb[q];
            int k = c4 + q * 4;
            int rs_ = r ^ (k & 16);            // same for k..k+3
            As[k+0][rs_] = va.x; As[k+1][rs_] = va.y; As[k+2][rs_] = va.z; As[k+3][rs_] = va.w;
            Bs[k+0][rs_] = vb.x; Bs[k+1][rs_] = vb.y; Bs[k+2][rs_] = vb.z; Bs[k+3][rs_] = vb.w;
        }
    }
    __syncthreads();
    int tx = tid & 15, ty = tid >> 4;
    float acc[4][4] = {};
#pragma unroll 8
    for (int k = 0; k < 64; ++k) {
        int kx = k & 16;
        float4 av = *(const float4*)&As[k][(ty * 4) ^ kx];
        float4 bv = *(const float4*)&Bs[k][(tx * 4) ^ kx];
        float aa[4] = {av.x, av.y, av.z, av.w};
        float bb[4] = {bv.x, bv.y, bv.z, bv.w};
#pragma unroll
        for (int r = 0; r < 4; ++r)
#pragma unroll
            for (int c = 0; c < 4; ++c)
                acc[r][c] += aa[r] * bb[c];
    }
    // --- epilogue: quantized store + fused S row/col sums (S = dot = acc) ---
    int lane = tid & 63;
#pragma unroll
    for (int r = 0; r < 4; ++r) {
        // quantized store of cost = 1 - dot
        ushort4 qv;
        float c0 = fminf(fmaxf(1.0f - acc[r][0], 0.0f), 2.0f);
        float c1 = fminf(fmaxf(1.0f - acc[r][1], 0.0f), 2.0f);
        float c2 = fminf(fmaxf(1.0f - acc[r][2], 0.0f), 2.0f);
        float c3 = fminf(fmaxf(1.0f - acc[r][3], 0.0f), 2.0f);
        qv.x = (unsigned short)__float2uint_rn(c0 * QSCALE);
        qv.y = (unsigned short)__float2uint_rn(c1 * QSCALE);
        qv.z = (unsigned short)__float2uint_rn(c2 * QSCALE);
        qv.w = (unsigned short)__float2uint_rn(c3 * QSCALE);
        *(ushort4*)&C16[((size_t)b * PP + i0 + ty * 4 + r) * PP + j0 + tx * 4] = qv;
        // row sum: reduce over tx (lanes sharing ty)
        float rowacc = acc[r][0] + acc[r][1] + acc[r][2] + acc[r][3];
#pragma unroll
        for (int m = 1; m < 16; m <<= 1) rowacc += __shfl_xor(rowacc, m, 64);
        if ((lane & 15) == 0) atomicAdd(&rowS[b * PP + i0 + ty * 4 + r], rowacc);
    }
#pragma unroll
    for (int c = 0; c < 4; ++c)
        atomicAdd(&csum_s[tx * 4 + c], acc[0][c] + acc[1][c] + acc[2][c] + acc[3][c]);
    __syncthreads();
    if (tid < 64) atomicAdd(&colS[b * PP + j0 + tid], csum_s[tid]);
}

// ---- weights: l1norm(clip(l1norm(mean(S)))) then store eps*log(w + 1e-8) ---
__device__ __forceinline__ float blockReduceSum256(float v, float* sh) {
    v = waveAllSum(v);
    int lane = threadIdx.x & 63, w = threadIdx.x >> 6;
    if (lane == 0) sh[w] = v;
    __syncthreads();
    float r = sh[0] + sh[1] + sh[2] + sh[3];
    __syncthreads();
    return r;
}

__global__ void weights_kernel(const float* __restrict__ rowS, const float* __restrict__ colS,
                               float* __restrict__ elm, float* __restrict__ eln) {
    __shared__ float sh[4];
    int b = blockIdx.x & 7;
    bool isB = blockIdx.x >= 8;
    const float* src = (isB ? colS : rowS) + b * PP;
    float* dst = (isB ? eln : elm) + b * PP;
    int tid = threadIdx.x;
    float x[8];
    float sabs = 0.0f;
#pragma unroll
    for (int q = 0; q < 8; ++q) {
        x[q] = src[tid + q * 256] * (1.0f / (float)PP);
        sabs += fabsf(x[q]);
    }
    sabs = blockReduceSum256(sabs, sh);
    float inv1 = 1.0f / fmaxf(sabs, 1e-12f);
    float spos = 0.0f;
#pragma unroll
    for (int q = 0; q < 8; ++q) {
        x[q] = fmaxf(x[q] * inv1, 0.0f);
        spos += x[q];
    }
    spos = blockReduceSum256(spos, sh);
    float inv2 = 1.0f / fmaxf(spos, 1e-12f);
#pragma unroll
    for (int q = 0; q < 8; ++q)
        dst[tid + q * 256] = EPSF * logf(x[q] * inv2 + 1e-8f);
}

// ---- u update: wave per row over u16 C, uint4 loads, shuffle-only ----------
__global__ __launch_bounds__(256) void u_update_kernel(const unsigned short* __restrict__ C16,
        const float* __restrict__ v, const float* __restrict__ elm,
        float* __restrict__ u, float* __restrict__ du, const int* __restrict__ conv) {
    if (*conv) return;
    int wv = threadIdx.x >> 6, lane = threadIdx.x & 63;
    int bi = blockIdx.x * 4 + wv;
    int b = bi >> 11;
    const uint4*  row = (const uint4*)(C16 + (size_t)bi * PP);   // 256 uint4/row
    const float4* vb  = (const float4*)(v + b * PP);
    float x[32];
    float m = NEG_INF;
#pragma unroll
    for (int g = 0; g < 4; ++g) {
        int idx = g * 64 + lane;
        uint4  q  = row[idx];
        float4 v0 = vb[idx * 2];
        float4 v1 = vb[idx * 2 + 1];
        float* xp = &x[g * 8];
        xp[0] = fmaf((float)(q.x & 0xffffu), -S_DEQ, v0.x);
        xp[1] = fmaf((float)(q.x >> 16),     -S_DEQ, v0.y);
        xp[2] = fmaf((float)(q.y & 0xffffu), -S_DEQ, v0.z);
        xp[3] = fmaf((float)(q.y >> 16),     -S_DEQ, v0.w);
        xp[4] = fmaf((float)(q.z & 0xffffu), -S_DEQ, v1.x);
        xp[5] = fmaf((float)(q.z >> 16),     -S_DEQ, v1.y);
        xp[6] = fmaf((float)(q.w & 0xffffu), -S_DEQ, v1.z);
        xp[7] = fmaf((float)(q.w >> 16),     -S_DEQ, v1.w);
#pragma unroll
        for (int k = 0; k < 8; ++k) m = fmaxf(m, xp[k]);
    }
    m = waveAllMax(m);
    float s = 0.0f;
#pragma unroll
    for (int k = 0; k < 32; ++k) s += __expf((x[k] - m) * RCPE);
    s = waveAllSum(s);
    if (lane == 0) {
        float unew = elm[bi] - m - EPSF * logf(s);
        du[bi] = fabsf(unew - u[bi]);
        u[bi] = unew;
    }
}

// ---- err reduce: one block; sets conv --------------------------------------
__global__ __launch_bounds__(1024) void err_reduce_kernel(const float* __restrict__ du,
                                                          int* __restrict__ conv) {
    if (*conv) return;
    __shared__ float sh[16];
    int t = threadIdx.x;
    float s = 0.0f;
#pragma unroll
    for (int q = 0; q < 16; ++q) s += du[t + q * 1024];
    s = waveAllSum(s);
    if ((t & 63) == 0) sh[t >> 6] = s;
    __syncthreads();
    if (t == 0) {
        float tot = 0.0f;
#pragma unroll
        for (int w = 0; w < 16; ++w) tot += sh[w];
        if (tot * (1.0f / (float)NB) < THRESHF) *conv = 1;
    }
}

// ---- v partials: thread owns 8 cols, online LSE over 32 rows (groups of 4) -
__global__ __launch_bounds__(256) void v_part_kernel(const unsigned short* __restrict__ C16,
        const float* __restrict__ u, float* __restrict__ vmp, float* __restrict__ vsp,
        const int* __restrict__ conv) {
    if (*conv) return;
    int rc = blockIdx.x, b = blockIdx.y;
    int r0 = rc * 32;
    int j  = threadIdx.x * 8;
    __shared__ float ush[32];
    if (threadIdx.x < 32) ush[threadIdx.x] = u[b * PP + r0 + threadIdx.x];
    __syncthreads();
    const unsigned short* base = C16 + ((size_t)b * PP + r0) * PP + j;
    float m[8], s[8];
#pragma unroll
    for (int c = 0; c < 8; ++c) { m[c] = NEG_INF; s[c] = 0.0f; }
    for (int g = 0; g < 8; ++g) {
        float x[4][8];
#pragma unroll
        for (int k = 0; k < 4; ++k) {
            uint4 q = *(const uint4*)(base + (size_t)(g * 4 + k) * PP);
            float uu = ush[g * 4 + k];
            x[k][0] = fmaf((float)(q.x & 0xffffu), -S_DEQ, uu);
            x[k][1] = fmaf((float)(q.x >> 16),     -S_DEQ, uu);
            x[k][2] = fmaf((float)(q.y & 0xffffu), -S_DEQ, uu);
            x[k][3] = fmaf((float)(q.y >> 16),     -S_DEQ, uu);
            x[k][4] = fmaf((float)(q.z & 0xffffu), -S_DEQ, uu);
            x[k][5] = fmaf((float)(q.z >> 16),     -S_DEQ, uu);
            x[k][6] = fmaf((float)(q.w & 0xffffu), -S_DEQ, uu);
            x[k][7] = fmaf((float)(q.w >> 16),     -S_DEQ, uu);
        }
#pragma unroll
        for (int c = 0; c < 8; ++c) {
            float gm = fmaxf(fmaxf(x[0][c], x[1][c]), fmaxf(x[2][c], x[3][c]));
            float nm = fmaxf(m[c], gm);
            float acc = __expf((x[0][c] - nm) * RCPE) + __expf((x[1][c] - nm) * RCPE)
                      + __expf((x[2][c] - nm) * RCPE) + __expf((x[3][c] - nm) * RCPE);
            s[c] = s[c] * __expf((m[c] - nm) * RCPE) + acc;
            m[c] = nm;
        }
    }
    size_t o = (size_t)(rc * NB + b) * PP + j;
    *(float4*)&vmp[o]     = make_float4(m[0], m[1], m[2], m[3]);
    *(float4*)&vmp[o + 4] = make_float4(m[4], m[5], m[6], m[7]);
    *(float4*)&vsp[o]     = make_float4(s[0], s[1], s[2], s[3]);
    *(float4*)&vsp[o + 4] = make_float4(s[4], s[5], s[6], s[7]);
}

__global__ void v_combine_kernel(const float* __restrict__ vmp, const float* __restrict__ vsp,
                                 const float* __restrict__ eln, float* __restrict__ v,
                                 const int* __restrict__ conv) {
    if (*conv) return;
    int idx = blockIdx.x * 256 + threadIdx.x;   // 64 blocks -> 16384
    float M = NEG_INF, S = 0.0f;
#pragma unroll
    for (int rc = 0; rc < 64; ++rc) {
        float m2 = vmp[(size_t)rc * (NB * PP) + idx];
        float s2 = vsp[(size_t)rc * (NB * PP) + idx];
        float nm = fmaxf(M, m2);
        S = S * __expf((M - nm) * RCPE) + s2 * __expf((m2 - nm) * RCPE);
        M = nm;
    }
    v[idx] = eln[idx] - M - EPSF * logf(S);
}

// ---- final: D[b] = sum_ij exp((u_i + v_j - C_ij)/eps) * C_ij ---------------
__global__ __launch_bounds__(256) void emd_kernel(const unsigned short* __restrict__ C16,
        const float* __restrict__ u, const float* __restrict__ v, float* __restrict__ out) {
    __shared__ float sh[4];
    int wv = threadIdx.x >> 6, lane = threadIdx.x & 63;
    int bi = blockIdx.x * 4 + wv;
    int b = bi >> 11;
    const uint4*  row = (const uint4*)(C16 + (size_t)bi * PP);
    const float4* vb  = (const float4*)(v + b * PP);
    float ui = u[bi];
    float s = 0.0f;
#pragma unroll
    for (int g = 0; g < 4; ++g) {
        int idx = g * 64 + lane;
        uint4  q  = row[idx];
        float4 v0 = vb[idx * 2];
        float4 v1 = vb[idx * 2 + 1];
        float c[8];
        c[0] = (float)(q.x & 0xffffu) * S_DEQ; c[1] = (float)(q.x >> 16) * S_DEQ;
        c[2] = (float)(q.y & 0xffffu) * S_DEQ; c[3] = (float)(q.y >> 16) * S_DEQ;
        c[4] = (float)(q.z & 0xffffu) * S_DEQ; c[5] = (float)(q.z >> 16) * S_DEQ;
        c[6] = (float)(q.w & 0xffffu) * S_DEQ; c[7] = (float)(q.w >> 16) * S_DEQ;
        float vv[8] = {v0.x, v0.y, v0.z, v0.w, v1.x, v1.y, v1.z, v1.w};
#pragma unroll
        for (int k = 0; k < 8; ++k)
            s += __expf((ui + vv[k] - c[k]) * RCPE) * c[k];
    }
    s = waveAllSum(s);
    if (lane == 0) sh[wv] = s;
    __syncthreads();
    if (threadIdx.x == 0) atomicAdd(&out[b], sh[0] + sh[1] + sh[2] + sh[3]);
}

extern "C" void kernel_launch(void* const* d_in, const int* in_sizes, int n_in,
                              void* d_out, int out_size, void* d_ws, size_t ws_size,
                              hipStream_t stream) {
    const float* a = (const float*)d_in[0];
    const float* b = (const float*)d_in[1];
    float* out = (float*)d_out;

    char* ws = (char*)d_ws;
    size_t off = 0;
    const size_t szC16 = (size_t)NB * PP * PP * 2;   // 64 MB
    const size_t szAN  = (size_t)NB * PP * DD * 4;   // 4 MB
    const size_t szPART= (size_t)64 * NB * PP * 4;   // 4 MB
    const size_t szV   = (size_t)NB * PP * 4;        // 64 KB
    unsigned short* C16 = (unsigned short*)(ws + off); off += szC16;
    float* an      = (float*)(ws + off); off += szAN;
    float* bn      = (float*)(ws + off); off += szAN;
    float* vmp     = (float*)(ws + off); off += szPART;
    float* vsp     = (float*)(ws + off); off += szPART;
    float* rowS    = (float*)(ws + off); off += szV;
    float* colS    = (float*)(ws + off); off += szV;
    float* elm     = (float*)(ws + off); off += szV;
    float* eln     = (float*)(ws + off); off += szV;
    float* u       = (float*)(ws + off); off += szV;
    float* v       = (float*)(ws + off); off += szV;
    float* du      = (float*)(ws + off); off += szV;
    int*   conv    = (int*)  (ws + off); off += 64;
    if (ws_size < off) return;

    init_kernel<<<64, 256, 0, stream>>>(u, v, rowS, colS, conv, out);
    norm_kernel<<<(2 * NB * PP) / 4, 256, 0, stream>>>(a, b, an, bn);
    cost_kernel<<<dim3(PP / 64, PP / 64, NB), 256, 0, stream>>>(an, bn, C16, rowS, colS);
    weights_kernel<<<16, 256, 0, stream>>>(rowS, colS, elm, eln);
    for (int it = 0; it < TMAX; ++it) {
        u_update_kernel<<<NB * PP / 4, 256, 0, stream>>>(C16, v, elm, u, du, conv);
        v_part_kernel<<<dim3(64, NB), 256, 0, stream>>>(C16, u, vmp, vsp, conv);
        v_combine_kernel<<<64, 256, 0, stream>>>(vmp, vsp, eln, v, conv);
        err_reduce_kernel<<<1, 1024, 0, stream>>>(du, conv);
    }
    emd_kernel<<<NB * PP / 4, 256, 0, stream>>>(C16, u, v, out);
}